// Round 2
// baseline (622.488 us; speedup 1.0000x reference)
//
#include <hip/hip_runtime.h>
#include <math.h>

// Problem: N=65536 positions (16x64x64), K=512 slots, D=64
// Output layout (floats): z_q [16,64,64,64] | hard_indices [16,64,64] | KL | commit
#define IDX_OFF 4194304
#define KL_OFF  4259840
#define CM_OFF  4259841
#define LOG_K   6.238324625039508f   // ln(512)

#define PITCH_A 516     // A[row][k]: phase1 codebook-T [c][k], phase2/3 soft [pos][k]
#define PITCH_T 68      // phase-3 codebook tile [k(64)][c(64)+pad]

__device__ __forceinline__ float wave_sum(float v){
#pragma unroll
  for (int m = 1; m < 64; m <<= 1) v += __shfl_xor(v, m, 64);
  return v;
}
__device__ __forceinline__ float wave_max(float v){
#pragma unroll
  for (int m = 1; m < 64; m <<= 1) v = fmaxf(v, __shfl_xor(v, m, 64));
  return v;
}

struct SMem {
  float A[64 * PITCH_A];                  // 132096 B
  union {
    struct { float Z[64 * 64]; float CC[512]; float ZZ[64]; } p1;  // 18688 B
    float Zc[64 * PITCH_T];                                        // 17408 B
  } u;
  float RED[32];
};  // total 150912 B < 160 KiB

__global__ __launch_bounds__(1024) void vq_fused(
    const float* __restrict__ ze, const float* __restrict__ cbk,
    const float* __restrict__ uin, float* __restrict__ out)
{
  __shared__ SMem sm;
  const int tid  = threadIdx.x;
  const int lane = tid & 63;
  const int wv   = tid >> 6;
  const int blk  = blockIdx.x;      // tile = one (b,h) row, w = 0..63
  const int bb   = blk >> 6;
  const int hh   = blk & 63;
  const int n0   = blk << 6;

  // ---- stage codebook transposed: A[c*PITCH_A + k] = cbk[k][c]
  // thread: k = (tid&63) + 64*it, c0 = (tid>>6)*4  -> LDS writes conflict-free (bank=k%32)
  {
    const int k0 = tid & 63;
    const int c0 = (tid >> 6) << 2;
#pragma unroll
    for (int it = 0; it < 8; ++it){
      const int k = k0 + (it << 6);
      const float4 v = *(const float4*)(cbk + k * 64 + c0);
      sm.A[(c0 + 0) * PITCH_A + k] = v.x;
      sm.A[(c0 + 1) * PITCH_A + k] = v.y;
      sm.A[(c0 + 2) * PITCH_A + k] = v.z;
      sm.A[(c0 + 3) * PITCH_A + k] = v.w;
    }
  }
  // ---- stage z tile: Z[c*64 + w] = ze[bb][c][hh][w]
  {
    const float* zb = ze + ((size_t)bb << 18) + (hh << 6);
#pragma unroll
    for (int it = 0; it < 4; ++it){
      const int idx = tid + (it << 10);
      const int c = idx >> 6, w = idx & 63;
      sm.u.p1.Z[idx] = zb[(c << 12) + w];
    }
  }
  __syncthreads();

  // ---- norms
  if (tid < 512){
    float s = 0.f;
#pragma unroll 8
    for (int c = 0; c < 64; ++c){ const float v = sm.A[c * PITCH_A + tid]; s = fmaf(v, v, s); }
    sm.u.p1.CC[tid] = s;
  } else if (tid < 576){
    const int p = tid - 512;
    float s = 0.f;
#pragma unroll 8
    for (int c = 0; c < 64; ++c){ const float v = sm.u.p1.Z[(c << 6) + p]; s = fmaf(v, v, s); }
    sm.u.p1.ZZ[p] = s;
  }
  __syncthreads();

  // ---- phase 1: dots. wave -> 4 positions, lane -> 8 slots: k = 4*lane + 256*j + i
  const int q0 = wv << 2;
  const int kq = lane << 2;
  float acc[4][8];
#pragma unroll
  for (int pp = 0; pp < 4; ++pp)
#pragma unroll
    for (int j = 0; j < 8; ++j) acc[pp][j] = 0.f;

#pragma unroll 4
  for (int c = 0; c < 64; ++c){
    const float4 cv0 = *(const float4*)&sm.A[c * PITCH_A + kq];        // b128, data-floor
    const float4 cv1 = *(const float4*)&sm.A[c * PITCH_A + kq + 256];
    float zv[4];
#pragma unroll
    for (int pp = 0; pp < 4; ++pp) zv[pp] = sm.u.p1.Z[(c << 6) + q0 + pp];  // broadcast
#pragma unroll
    for (int pp = 0; pp < 4; ++pp){
      acc[pp][0] = fmaf(zv[pp], cv0.x, acc[pp][0]);
      acc[pp][1] = fmaf(zv[pp], cv0.y, acc[pp][1]);
      acc[pp][2] = fmaf(zv[pp], cv0.z, acc[pp][2]);
      acc[pp][3] = fmaf(zv[pp], cv0.w, acc[pp][3]);
      acc[pp][4] = fmaf(zv[pp], cv1.x, acc[pp][4]);
      acc[pp][5] = fmaf(zv[pp], cv1.y, acc[pp][5]);
      acc[pp][6] = fmaf(zv[pp], cv1.z, acc[pp][6]);
      acc[pp][7] = fmaf(zv[pp], cv1.w, acc[pp][7]);
    }
  }
  // logits = 2*dot - ||c||^2 - ||z||^2
  {
    const float4 cc0 = *(const float4*)&sm.u.p1.CC[kq];
    const float4 cc1 = *(const float4*)&sm.u.p1.CC[kq + 256];
    const float cc[8] = {cc0.x, cc0.y, cc0.z, cc0.w, cc1.x, cc1.y, cc1.z, cc1.w};
#pragma unroll
    for (int pp = 0; pp < 4; ++pp){
      const float zz = sm.u.p1.ZZ[q0 + pp];
#pragma unroll
      for (int j = 0; j < 8; ++j) acc[pp][j] = fmaf(2.f, acc[pp][j], -cc[j] - zz);
    }
  }
  __syncthreads();   // codebook-T region of A becomes soft-weight storage

  // ---- phase 2: gumbel softmax + probs + KL/commit
  float pa = 0.f;      // per-lane partial of sum_j p_j * logit_j (shared by KL & commit)
  float kluni = 0.f;   // wave-uniform per-position terms
#pragma unroll 1
  for (int pp = 0; pp < 4; ++pp){
    const int q = q0 + pp;
    const int n = n0 + q;
    const float* urow = uin + ((size_t)n << 9);
    const float4 u0 = *(const float4*)(urow + kq);
    const float4 u1 = *(const float4*)(urow + kq + 256);
    const float uu[8] = {u0.x, u0.y, u0.z, u0.w, u1.x, u1.y, u1.z, u1.w};
    float a[8], e[8];
    float amax = -3.4e38f; int kbest = 0;
#pragma unroll
    for (int j = 0; j < 8; ++j){
      const float g  = -__logf(-__logf(uu[j] + 1e-10f) + 1e-10f);
      const float aj = (acc[pp][j] + g) * 2.0f;              // (logits+gumbel)/T, T=0.5
      a[j] = aj;
      const int kk = kq + ((j < 4) ? j : (252 + j));         // 4*lane+j | 4*lane+256+(j-4)
      if (aj > amax){ amax = aj; kbest = kk; }               // jj ascending == k ascending
    }
#pragma unroll
    for (int m = 1; m < 64; m <<= 1){                        // argmax, min-index ties
      const float vo = __shfl_xor(amax, m, 64);
      const int   io = __shfl_xor(kbest, m, 64);
      if (vo > amax || (vo == amax && io < kbest)){ amax = vo; kbest = io; }
    }
    float s1 = 0.f;
#pragma unroll
    for (int j = 0; j < 8; ++j){ e[j] = __expf(a[j] - amax); s1 += e[j]; }
    s1 = wave_sum(s1);
    const float inv1 = 1.0f / s1;
    *(float4*)&sm.A[q * PITCH_A + kq]       = make_float4(e[0]*inv1, e[1]*inv1, e[2]*inv1, e[3]*inv1);
    *(float4*)&sm.A[q * PITCH_A + kq + 256] = make_float4(e[4]*inv1, e[5]*inv1, e[6]*inv1, e[7]*inv1);
    if (lane == 0) out[IDX_OFF + n] = (float)kbest;

    // probs = softmax(logits); KL_pos = sum p*(logit-lmax) - log(s2) + LOG_K ; commit = -sum p*logit
    float lmax = acc[pp][0];
#pragma unroll
    for (int j = 1; j < 8; ++j) lmax = fmaxf(lmax, acc[pp][j]);
    lmax = wave_max(lmax);
    float s2 = 0.f, t1 = 0.f;
#pragma unroll
    for (int j = 0; j < 8; ++j){
      const float ee = __expf(acc[pp][j] - lmax);
      s2 += ee; t1 = fmaf(ee, acc[pp][j], t1);
    }
    s2 = wave_sum(s2);
    const float inv2 = 1.0f / s2;
    pa = fmaf(t1, inv2, pa);                    // per-lane partial of sum p*logit
    kluni += LOG_K - lmax - __logf(s2);         // uniform; count once per position
  }
  {
    const float P = wave_sum(pa);
    if (lane == 0){ sm.RED[wv] = P + kluni; sm.RED[wv + 16] = -P; }
  }
  __syncthreads();   // gates soft-weight visibility + RED
  if (tid == 0){
    float tk = 0.f, tc = 0.f;
#pragma unroll
    for (int i = 0; i < 16; ++i){ tk += sm.RED[i]; tc += sm.RED[i + 16]; }
    atomicAdd(out + KL_OFF, tk * 0.0625f);
    atomicAdd(out + CM_OFF, tc * 0.0625f);
  }

  // ---- phase 3: z_q[w][c] = sum_k soft[w][k] * cbk[k][c], codebook k-tiled via LDS
  const int w  = tid & 63;
  const int c0 = (tid >> 6) << 2;     // wave-uniform channel quad
  float o0 = 0.f, o1 = 0.f, o2 = 0.f, o3 = 0.f;
  const int srow = tid >> 4;          // staging: row within tile
  const int scq  = (tid & 15) << 2;   // staging: channel quad
#pragma unroll 1
  for (int kt = 0; kt < 8; ++kt){
    {  // stage 64 codebook rows -> Zc  (global coalesced, LDS b128 at data floor)
      const float4 v = *(const float4*)(cbk + (((kt << 6) + srow) << 6) + scq);
      *(float4*)&sm.u.Zc[srow * PITCH_T + scq] = v;
    }
    __syncthreads();
#pragma unroll 4
    for (int kk = 0; kk < 16; ++kk){
      const float4 s4 = *(const float4*)&sm.A[w * PITCH_A + (kt << 6) + (kk << 2)];
      const float4 r0 = *(const float4*)&sm.u.Zc[((kk << 2) + 0) * PITCH_T + c0]; // broadcast
      const float4 r1 = *(const float4*)&sm.u.Zc[((kk << 2) + 1) * PITCH_T + c0];
      const float4 r2 = *(const float4*)&sm.u.Zc[((kk << 2) + 2) * PITCH_T + c0];
      const float4 r3 = *(const float4*)&sm.u.Zc[((kk << 2) + 3) * PITCH_T + c0];
      o0 = fmaf(s4.x, r0.x, o0); o1 = fmaf(s4.x, r0.y, o1); o2 = fmaf(s4.x, r0.z, o2); o3 = fmaf(s4.x, r0.w, o3);
      o0 = fmaf(s4.y, r1.x, o0); o1 = fmaf(s4.y, r1.y, o1); o2 = fmaf(s4.y, r1.z, o2); o3 = fmaf(s4.y, r1.w, o3);
      o0 = fmaf(s4.z, r2.x, o0); o1 = fmaf(s4.z, r2.y, o1); o2 = fmaf(s4.z, r2.z, o2); o3 = fmaf(s4.z, r2.w, o3);
      o0 = fmaf(s4.w, r3.x, o0); o1 = fmaf(s4.w, r3.y, o1); o2 = fmaf(s4.w, r3.z, o2); o3 = fmaf(s4.w, r3.w, o3);
    }
    __syncthreads();   // protect Zc before next tile's staging
  }
  {
    float* zq = out + ((size_t)bb << 18) + (hh << 6) + w;   // z_q[bb][c][hh][w]
    zq[(size_t)(c0 + 0) << 12] = o0;    // coalesced (w contiguous across lanes)
    zq[(size_t)(c0 + 1) << 12] = o1;
    zq[(size_t)(c0 + 2) << 12] = o2;
    zq[(size_t)(c0 + 3) << 12] = o3;
  }
}

extern "C" void kernel_launch(void* const* d_in, const int* in_sizes, int n_in,
                              void* d_out, int out_size, void* d_ws, size_t ws_size,
                              hipStream_t stream){
  const float* ze  = (const float*)d_in[0];
  const float* cbk = (const float*)d_in[1];
  const float* uin = (const float*)d_in[2];
  float* out = (float*)d_out;
  hipMemsetAsync(out + KL_OFF, 0, 2 * sizeof(float), stream);
  vq_fused<<<dim3(1024), dim3(1024), 0, stream>>>(ze, cbk, uin, out);
}

// Round 3
// 545.095 us; speedup vs baseline: 1.1420x; 1.1420x over previous
//
#include <hip/hip_runtime.h>
#include <math.h>

// Problem: N=65536 positions (16x64x64), K=512 slots, D=64
// Output layout (floats): z_q [16,64,64,64] | hard_indices [16,64,64] | KL | commit
#define IDX_OFF 4194304
#define KL_OFF  4259840
#define CM_OFF  4259841
#define LOG_K   6.238324625039508f   // ln(512)

#define PITCH_A 512     // codebook-T [c][k]: contiguous-lane b128 reads, bank-agnostic
#define PITCH_S 513     // soft [pos][k]: 513%32==1 -> lane-bank-stride 1 (conflict-free)
#define PITCH_T 68      // phase-3 codebook tile [k][c]

__device__ __forceinline__ float wave_sum(float v){
#pragma unroll
  for (int m = 1; m < 64; m <<= 1) v += __shfl_xor(v, m, 64);
  return v;
}
__device__ __forceinline__ float wave_max(float v){
#pragma unroll
  for (int m = 1; m < 64; m <<= 1) v = fmaxf(v, __shfl_xor(v, m, 64));
  return v;
}

struct SMem {
  union {
    float A[64 * PITCH_A];   // phase 1: codebook transposed [c][k]   (131072 B)
    float S[64 * PITCH_S];   // phase 2/3: soft weights [pos][k]      (131328 B)
  } big;
  union {
    struct { float Z[64 * 64]; float CC[512]; float ZZ[64]; } p1;    // 18688 B
    float Zc[64 * PITCH_T];                                          // 17408 B
  } u;
  float RED[32];
};  // 150144 B < 160 KiB

__global__ __launch_bounds__(1024) void vq_fused(
    const float* __restrict__ ze, const float* __restrict__ cbk,
    const float* __restrict__ uin, float* __restrict__ out)
{
  __shared__ SMem sm;
  const int tid  = threadIdx.x;
  const int lane = tid & 63;
  const int wv   = tid >> 6;
  const int blk  = blockIdx.x;      // tile = one (b,h) row, w = 0..63
  const int bb   = blk >> 6;
  const int hh   = blk & 63;
  const int n0   = blk << 6;

  // ---- stage codebook transposed: A[c][k] = cbk[k][c]; lane-stride-1 writes (free)
  {
    const int k0  = tid & 63;
    const int c0s = (tid >> 6) << 2;
#pragma unroll
    for (int it = 0; it < 8; ++it){
      const int k = k0 + (it << 6);
      const float4 v = *(const float4*)(cbk + k * 64 + c0s);
      sm.big.A[(c0s + 0) * PITCH_A + k] = v.x;
      sm.big.A[(c0s + 1) * PITCH_A + k] = v.y;
      sm.big.A[(c0s + 2) * PITCH_A + k] = v.z;
      sm.big.A[(c0s + 3) * PITCH_A + k] = v.w;
    }
  }
  // ---- stage z tile: Z[c][w] = ze[bb][c][hh][w]
  {
    const float* zb = ze + ((size_t)bb << 18) + (hh << 6);
#pragma unroll
    for (int it = 0; it < 4; ++it){
      const int idx = tid + (it << 10);
      const int c = idx >> 6, w = idx & 63;
      sm.u.p1.Z[idx] = zb[(c << 12) + w];
    }
  }
  __syncthreads();

  // ---- norms
  if (tid < 512){
    float s = 0.f;
#pragma unroll 8
    for (int c = 0; c < 64; ++c){ const float v = sm.big.A[c * PITCH_A + tid]; s = fmaf(v, v, s); }
    sm.u.p1.CC[tid] = s;
  } else if (tid < 576){
    const int p = tid - 512;
    float s = 0.f;
#pragma unroll 8
    for (int c = 0; c < 64; ++c){ const float v = sm.u.p1.Z[(c << 6) + p]; s = fmaf(v, v, s); }
    sm.u.p1.ZZ[p] = s;
  }
  __syncthreads();

  // ---- phase 1: dots. wave -> 4 positions, lane -> k quads {4*lane, 4*lane+256}
  const int q0 = wv << 2;
  const int kq = lane << 2;
  float acc[4][8];
#pragma unroll
  for (int pp = 0; pp < 4; ++pp)
#pragma unroll
    for (int j = 0; j < 8; ++j) acc[pp][j] = 0.f;

#pragma unroll 4
  for (int c = 0; c < 64; ++c){
    const float4 cv0 = *(const float4*)&sm.big.A[c * PITCH_A + kq];        // lane-contig b128
    const float4 cv1 = *(const float4*)&sm.big.A[c * PITCH_A + kq + 256];
    const float4 zq4 = *(const float4*)&sm.u.p1.Z[(c << 6) + q0];          // b128 broadcast
    const float zv[4] = {zq4.x, zq4.y, zq4.z, zq4.w};
#pragma unroll
    for (int pp = 0; pp < 4; ++pp){
      acc[pp][0] = fmaf(zv[pp], cv0.x, acc[pp][0]);
      acc[pp][1] = fmaf(zv[pp], cv0.y, acc[pp][1]);
      acc[pp][2] = fmaf(zv[pp], cv0.z, acc[pp][2]);
      acc[pp][3] = fmaf(zv[pp], cv0.w, acc[pp][3]);
      acc[pp][4] = fmaf(zv[pp], cv1.x, acc[pp][4]);
      acc[pp][5] = fmaf(zv[pp], cv1.y, acc[pp][5]);
      acc[pp][6] = fmaf(zv[pp], cv1.z, acc[pp][6]);
      acc[pp][7] = fmaf(zv[pp], cv1.w, acc[pp][7]);
    }
  }
  // logits = 2*dot - ||c||^2 - ||z||^2
  {
    const float4 cc0 = *(const float4*)&sm.u.p1.CC[kq];
    const float4 cc1 = *(const float4*)&sm.u.p1.CC[kq + 256];
    const float cc[8] = {cc0.x, cc0.y, cc0.z, cc0.w, cc1.x, cc1.y, cc1.z, cc1.w};
    const float4 zz4 = *(const float4*)&sm.u.p1.ZZ[q0];
    const float zz[4] = {zz4.x, zz4.y, zz4.z, zz4.w};
#pragma unroll
    for (int pp = 0; pp < 4; ++pp)
#pragma unroll
      for (int j = 0; j < 8; ++j) acc[pp][j] = fmaf(2.f, acc[pp][j], -cc[j] - zz[pp]);
  }
  __syncthreads();   // A dead; big union becomes soft-weight storage S

  // ---- phase 2: gumbel softmax + probs + KL/commit
  float pa = 0.f;      // per-lane partial of sum_j p_j * logit_j (shared by KL & commit)
  float kluni = 0.f;   // wave-uniform per-position terms
#pragma unroll 1
  for (int pp = 0; pp < 4; ++pp){
    const int q = q0 + pp;
    const int n = n0 + q;
    const float* urow = uin + ((size_t)n << 9);
    const float4 u0 = *(const float4*)(urow + kq);
    const float4 u1 = *(const float4*)(urow + kq + 256);
    const float uu[8] = {u0.x, u0.y, u0.z, u0.w, u1.x, u1.y, u1.z, u1.w};
    float a[8], e[8];
    float amax = -3.4e38f; int kbest = 0;
#pragma unroll
    for (int j = 0; j < 8; ++j){
      const float g  = -__logf(-__logf(uu[j] + 1e-10f) + 1e-10f);
      const float aj = (acc[pp][j] + g) * 2.0f;              // (logits+gumbel)/T, T=0.5
      a[j] = aj;
      const int kk = kq + ((j < 4) ? j : (252 + j));         // j ascending == k ascending
      if (aj > amax){ amax = aj; kbest = kk; }
    }
#pragma unroll
    for (int m = 1; m < 64; m <<= 1){                        // argmax, min-index ties
      const float vo = __shfl_xor(amax, m, 64);
      const int   io = __shfl_xor(kbest, m, 64);
      if (vo > amax || (vo == amax && io < kbest)){ amax = vo; kbest = io; }
    }
    float s1 = 0.f;
#pragma unroll
    for (int j = 0; j < 8; ++j){ e[j] = __expf(a[j] - amax); s1 += e[j]; }
    s1 = wave_sum(s1);
    const float inv1 = 1.0f / s1;
    float* srow = &sm.big.S[q * PITCH_S + kq];               // scalar writes (4-way, rare)
#pragma unroll
    for (int j = 0; j < 4; ++j) srow[j]       = e[j] * inv1;
#pragma unroll
    for (int j = 0; j < 4; ++j) srow[256 + j] = e[4 + j] * inv1;
    if (lane == 0) out[IDX_OFF + n] = (float)kbest;

    // probs = softmax(logits); KL_pos = sum p*logit - lmax - log(s2) + LOG_K; commit = -sum p*logit
    float lmax = acc[pp][0];
#pragma unroll
    for (int j = 1; j < 8; ++j) lmax = fmaxf(lmax, acc[pp][j]);
    lmax = wave_max(lmax);
    float s2 = 0.f, t1 = 0.f;
#pragma unroll
    for (int j = 0; j < 8; ++j){
      const float ee = __expf(acc[pp][j] - lmax);
      s2 += ee; t1 = fmaf(ee, acc[pp][j], t1);
    }
    s2 = wave_sum(s2);
    const float inv2 = 1.0f / s2;
    pa = fmaf(t1, inv2, pa);
    kluni += LOG_K - lmax - __logf(s2);
  }
  {
    const float P = wave_sum(pa);
    if (lane == 0){ sm.RED[wv] = P + kluni; sm.RED[wv + 16] = -P; }
  }
  __syncthreads();   // gates S visibility + RED
  if (tid == 0){
    float tk = 0.f, tc = 0.f;
#pragma unroll
    for (int i = 0; i < 16; ++i){ tk += sm.RED[i]; tc += sm.RED[i + 16]; }
    atomicAdd(out + KL_OFF, tk * 0.0625f);
    atomicAdd(out + CM_OFF, tc * 0.0625f);
  }

  // ---- phase 3: z_q[w][c] = sum_k S[w][k] * cbk[k][c], codebook k-tiled via LDS
  const int w  = tid & 63;            // position (= lane): S reads bank-stride-1 (free)
  const int c0 = (tid >> 6) << 2;     // wave-uniform channel quad (broadcast reads)
  float o0 = 0.f, o1 = 0.f, o2 = 0.f, o3 = 0.f;
  const int srow = tid >> 4;
  const int scq  = (tid & 15) << 2;
#pragma unroll 1
  for (int kt = 0; kt < 8; ++kt){
    {  // stage 64 codebook rows -> Zc (global coalesced)
      const float4 v = *(const float4*)(cbk + (((kt << 6) + srow) << 6) + scq);
      *(float4*)&sm.u.Zc[srow * PITCH_T + scq] = v;
    }
    __syncthreads();
    const float* sr = &sm.big.S[w * PITCH_S + (kt << 6)];
#pragma unroll 4
    for (int kk = 0; kk < 64; kk += 4){
      const float s0 = sr[kk + 0];                                    // b32, stride-1 banks
      const float s1 = sr[kk + 1];
      const float s2 = sr[kk + 2];
      const float s3 = sr[kk + 3];
      const float4 r0 = *(const float4*)&sm.u.Zc[(kk + 0) * PITCH_T + c0];  // broadcast
      const float4 r1 = *(const float4*)&sm.u.Zc[(kk + 1) * PITCH_T + c0];
      const float4 r2 = *(const float4*)&sm.u.Zc[(kk + 2) * PITCH_T + c0];
      const float4 r3 = *(const float4*)&sm.u.Zc[(kk + 3) * PITCH_T + c0];
      o0 = fmaf(s0, r0.x, o0); o1 = fmaf(s0, r0.y, o1); o2 = fmaf(s0, r0.z, o2); o3 = fmaf(s0, r0.w, o3);
      o0 = fmaf(s1, r1.x, o0); o1 = fmaf(s1, r1.y, o1); o2 = fmaf(s1, r1.z, o2); o3 = fmaf(s1, r1.w, o3);
      o0 = fmaf(s2, r2.x, o0); o1 = fmaf(s2, r2.y, o1); o2 = fmaf(s2, r2.z, o2); o3 = fmaf(s2, r2.w, o3);
      o0 = fmaf(s3, r3.x, o0); o1 = fmaf(s3, r3.y, o1); o2 = fmaf(s3, r3.z, o2); o3 = fmaf(s3, r3.w, o3);
    }
    __syncthreads();   // protect Zc before next tile's staging
  }
  {
    float* zq = out + ((size_t)bb << 18) + (hh << 6) + w;   // z_q[bb][c][hh][w]
    zq[(size_t)(c0 + 0) << 12] = o0;    // coalesced (w contiguous across lanes)
    zq[(size_t)(c0 + 1) << 12] = o1;
    zq[(size_t)(c0 + 2) << 12] = o2;
    zq[(size_t)(c0 + 3) << 12] = o3;
  }
}

extern "C" void kernel_launch(void* const* d_in, const int* in_sizes, int n_in,
                              void* d_out, int out_size, void* d_ws, size_t ws_size,
                              hipStream_t stream){
  const float* ze  = (const float*)d_in[0];
  const float* cbk = (const float*)d_in[1];
  const float* uin = (const float*)d_in[2];
  float* out = (float*)d_out;
  hipMemsetAsync(out + KL_OFF, 0, 2 * sizeof(float), stream);
  vq_fused<<<dim3(1024), dim3(1024), 0, stream>>>(ze, cbk, uin, out);
}

// Round 4
// 360.572 us; speedup vs baseline: 1.7264x; 1.5118x over previous
//
#include <hip/hip_runtime.h>
#include <math.h>

// N=65536 pos (16x64x64), K=512 slots, D=64.
// out: z_q [16,64,64,64] | idx [16,64,64] | KL | commit   (floats)
#define IDX_OFF 4194304
#define KL_OFF  4259840
#define CM_OFF  4259841
#define LOG_K   6.238324625039508f

typedef _Float16 half8 __attribute__((ext_vector_type(8)));
typedef float f32x4 __attribute__((ext_vector_type(4)));

union U32H { uint32_t u; _Float16 f[2]; };   // f[0]=lo16=hi-part, f[1]=hi16=lo-part

__device__ __forceinline__ uint32_t pack_hl(float x){
  _Float16 h = (_Float16)x;
  _Float16 l = (_Float16)(x - (float)h);
  U32H p; p.f[0] = h; p.f[1] = l;
  return p.u;
}
__device__ __forceinline__ float sh16sum(float v){
#pragma unroll
  for (int m = 1; m < 16; m <<= 1) v += __shfl_xor(v, m, 64);
  return v;
}
__device__ __forceinline__ float sh16max(float v){
#pragma unroll
  for (int m = 1; m < 16; m <<= 1) v = fmaxf(v, __shfl_xor(v, m, 64));
  return v;
}

struct SMem {
  uint32_t CBT[128*66];                 // codebook supertile packed (h,l) [slot][c]  33792B
  union { _Float16 et[32*130]; uint32_t et32[32*65]; } E;   // e fp16 [pos][slot] 8320B
  union { float ZT[32*66]; float ZB[64*33]; } Z;            // z [pos][c] / zq transpose 8448B
  float CC[512];
  float ZZ[32];
  float TMa[32*4], TMl[32*4];           // per-supertile tile maxes [pos][Ng]
  float SM1[32*4], SM2[32*4], ST[32*4], AMv[32*4];
  int   AMi[32*4];
  float RED[16];
};  // ~56.4 KB -> 2 blocks/CU

__global__ __launch_bounds__(512, 4) void vq_mfma(
    const float* __restrict__ ze, const float* __restrict__ cbk,
    const float* __restrict__ uin, float* __restrict__ out)
{
  __shared__ SMem sm;
  const int tid  = threadIdx.x;
  const int lane = tid & 63;
  const int l15  = lane & 15;
  const int quad = lane >> 4;          // 0..3
  const int wv   = tid >> 6;           // 0..7
  const int Mg   = wv >> 2;            // 0..1  (16-pos group)
  const int Ng   = wv & 3;             // 0..3  (32-slot stripe / 16-ch group)
  const int blk  = blockIdx.x;         // 2048 blocks, 32 positions each
  const int bb   = blk >> 7;
  const int hh   = (blk >> 1) & 63;
  const int w0   = (blk & 1) << 5;
  const int n0   = blk << 5;

  // ---- stage z transposed: ZT[w][c] = ze[bb][c][hh][w0+w]
  {
    const int c  = tid >> 3;
    const int w4 = (tid & 7) << 2;
    const float4 v = *(const float4*)(ze + ((size_t)bb << 18) + (c << 12) + (hh << 6) + w0 + w4);
    sm.Z.ZT[(w4 + 0)*66 + c] = v.x;
    sm.Z.ZT[(w4 + 1)*66 + c] = v.y;
    sm.Z.ZT[(w4 + 2)*66 + c] = v.z;
    sm.Z.ZT[(w4 + 3)*66 + c] = v.w;
  }
  // ---- ||c||^2 (each thread one slot; 128KB global, L2-hot)
  {
    const float* cp = cbk + tid * 64;
    float s = 0.f;
#pragma unroll
    for (int i = 0; i < 16; ++i){
      const float4 v = *(const float4*)(cp + (i << 2));
      s = fmaf(v.x, v.x, s); s = fmaf(v.y, v.y, s);
      s = fmaf(v.z, v.z, s); s = fmaf(v.w, v.w, s);
    }
    sm.CC[tid] = s;
  }
  __syncthreads();
  if (tid < 32){
    float s = 0.f;
#pragma unroll 8
    for (int c = 0; c < 64; ++c){ const float v = sm.Z.ZT[tid*66 + c]; s = fmaf(v, v, s); }
    sm.ZZ[tid] = s;
  }
  __syncthreads();

  // ---- hoist z A-frags (2 k-chunks of 32 c), fp16 2-term split
  half8 zh[2], zl[2];
#pragma unroll
  for (int kc = 0; kc < 2; ++kc){
    const float* zp = &sm.Z.ZT[(Mg*16 + l15)*66 + (kc << 5) + (quad << 3)];
#pragma unroll
    for (int j = 0; j < 8; ++j){
      const float x = zp[j];
      const _Float16 h = (_Float16)x;
      zh[kc][j] = h;
      zl[kc][j] = (_Float16)(x - (float)h);
    }
  }
  float zzv[4];
#pragma unroll
  for (int r = 0; r < 4; ++r) zzv[r] = sm.ZZ[Mg*16 + quad*4 + r];

  // ---- online-softmax state (per lane, 4 rows)
  float m1[4], s1[4], m2[4], s2[4], t1[4], am[4];
  int ki[4];
#pragma unroll
  for (int r = 0; r < 4; ++r){
    m1[r] = -3.0e38f; s1[r] = 0.f; m2[r] = -3.0e38f; s2[r] = 0.f;
    t1[r] = 0.f; am[r] = -3.0e38f; ki[r] = 0;
  }
  f32x4 zacc = {0.f, 0.f, 0.f, 0.f};

  // ================= supertile loop (4 x 128 slots) =================
#pragma unroll 1
  for (int st = 0; st < 4; ++st){
    __syncthreads();   // protect CBT/ET from previous iteration readers
    {  // stage codebook supertile, packed (h,l): CBT[slot][c]
      const int sl  = tid >> 2;            // 0..127
      const int c16 = (tid & 3) << 4;
      const float* gp = cbk + ((st << 7) + sl) * 64 + c16;
      uint32_t* wp = &sm.CBT[sl*66 + c16];
#pragma unroll
      for (int i = 0; i < 4; ++i){
        const float4 v = *(const float4*)(gp + (i << 2));
        wp[(i<<2)+0] = pack_hl(v.x); wp[(i<<2)+1] = pack_hl(v.y);
        wp[(i<<2)+2] = pack_hl(v.z); wp[(i<<2)+3] = pack_hl(v.w);
      }
    }
    __syncthreads();

    // ---- logits MFMA: D[pos 16 x slot 32] per wave, K=64, 4 split terms
    f32x4 accl[2];
    float lv[2][4], av[2][4];
#pragma unroll
    for (int nt = 0; nt < 2; ++nt){
      f32x4 acc = {0.f, 0.f, 0.f, 0.f};
      const int slotl = (Ng << 5) + (nt << 4) + l15;
#pragma unroll
      for (int kc = 0; kc < 2; ++kc){
        half8 bh, bl;
        const uint32_t* bp = &sm.CBT[slotl*66 + (kc << 5) + (quad << 3)];
#pragma unroll
        for (int j = 0; j < 8; ++j){ U32H t; t.u = bp[j]; bh[j] = t.f[0]; bl[j] = t.f[1]; }
        acc = __builtin_amdgcn_mfma_f32_16x16x32_f16(zh[kc], bh, acc, 0, 0, 0);
        acc = __builtin_amdgcn_mfma_f32_16x16x32_f16(zh[kc], bl, acc, 0, 0, 0);
        acc = __builtin_amdgcn_mfma_f32_16x16x32_f16(zl[kc], bh, acc, 0, 0, 0);
        acc = __builtin_amdgcn_mfma_f32_16x16x32_f16(zl[kc], bl, acc, 0, 0, 0);
      }
      accl[nt] = acc;
      const float ccv = sm.CC[(st << 7) + slotl];
#pragma unroll
      for (int r = 0; r < 4; ++r){
        const float l = fmaf(2.f, acc[r], -ccv - zzv[r]);   // logit
        lv[nt][r] = l;
        const int n = n0 + Mg*16 + quad*4 + r;
        const float uu = uin[(size_t)n * 512 + (st << 7) + slotl];
        const float g  = -__logf(-__logf(uu + 1e-10f) + 1e-10f);
        av[nt][r] = (l + g) * 2.0f;
      }
    }
    // ---- tile-local maxes -> LDS
#pragma unroll
    for (int r = 0; r < 4; ++r){
      float ta = sh16max(fmaxf(av[0][r], av[1][r]));
      float tl = sh16max(fmaxf(lv[0][r], lv[1][r]));
      if (l15 == 0){
        const int pos = Mg*16 + quad*4 + r;
        sm.TMa[pos*4 + Ng] = ta;
        sm.TMl[pos*4 + Ng] = tl;
      }
    }
    __syncthreads();
    // ---- merge maxes, online update, e-store, argmax
#pragma unroll
    for (int r = 0; r < 4; ++r){
      const int pos = Mg*16 + quad*4 + r;
      float M1n = m1[r], M2n = m2[r];
#pragma unroll
      for (int g = 0; g < 4; ++g){
        M1n = fmaxf(M1n, sm.TMa[pos*4 + g]);
        M2n = fmaxf(M2n, sm.TMl[pos*4 + g]);
      }
      const float sc1 = __expf(m1[r] - M1n);
      const float sc2 = __expf(m2[r] - M2n);
      float esum = 0.f, psum = 0.f, plsum = 0.f;
#pragma unroll
      for (int nt = 0; nt < 2; ++nt){
        const float e = __expf(av[nt][r] - M1n);
        esum += e;
        sm.E.et[pos*130 + (Ng << 5) + (nt << 4) + l15] = (_Float16)e;
        const float p = __expf(lv[nt][r] - M2n);
        psum += p;
        plsum = fmaf(p, lv[nt][r], plsum);
      }
      s1[r] = fmaf(s1[r], sc1, sh16sum(esum));
      s2[r] = fmaf(s2[r], sc2, sh16sum(psum));
      t1[r] = fmaf(t1[r], sc2, sh16sum(plsum));
      m1[r] = M1n; m2[r] = M2n;
      zacc[r] *= sc1;                     // flash rescale of z_q accumulator
      // argmax (value, min index on tie)
      float bv; int bi;
      {
        const int s0 = (st << 7) + (Ng << 5) + l15;
        if (av[0][r] >= av[1][r]) { bv = av[0][r]; bi = s0; }
        else                      { bv = av[1][r]; bi = s0 + 16; }
#pragma unroll
        for (int m = 1; m < 16; m <<= 1){
          const float vo = __shfl_xor(bv, m, 64);
          const int   io = __shfl_xor(bi, m, 64);
          if (vo > bv || (vo == bv && io < bi)){ bv = vo; bi = io; }
        }
      }
      if (bv > am[r]){ am[r] = bv; ki[r] = bi; }   // later tiles have larger k
    }
    __syncthreads();   // e-tile complete
    // ---- z_q MFMA: D[pos 16 x c 16] per wave, K=128 (this supertile)
#pragma unroll
    for (int kc3 = 0; kc3 < 4; ++kc3){
      union { uint32_t u[4]; half8 h; } af;
      const uint32_t* ap = &sm.E.et32[(Mg*16 + l15)*65 + (kc3 << 4) + (quad << 2)];
#pragma unroll
      for (int jj = 0; jj < 4; ++jj) af.u[jj] = ap[jj];
      half8 bh, bl;
      const uint32_t* bp = &sm.CBT[((kc3 << 5) + (quad << 3))*66 + (Ng << 4) + l15];
#pragma unroll
      for (int j = 0; j < 8; ++j){ U32H t; t.u = bp[j*66]; bh[j] = t.f[0]; bl[j] = t.f[1]; }
      zacc = __builtin_amdgcn_mfma_f32_16x16x32_f16(af.h, bh, zacc, 0, 0, 0);
      zacc = __builtin_amdgcn_mfma_f32_16x16x32_f16(af.h, bl, zacc, 0, 0, 0);
    }
  }
  // ================= end supertile loop =================

  __syncthreads();
  // ---- cross-wave (Ng) partial merges
  if (l15 == 0){
#pragma unroll
    for (int r = 0; r < 4; ++r){
      const int pos = Mg*16 + quad*4 + r;
      sm.SM1[pos*4 + Ng] = s1[r];
      sm.SM2[pos*4 + Ng] = s2[r];
      sm.ST [pos*4 + Ng] = t1[r];
      sm.AMv[pos*4 + Ng] = am[r];
      sm.AMi[pos*4 + Ng] = ki[r];
    }
  }
  __syncthreads();

  float klsum = 0.f, cmsum = 0.f;
#pragma unroll
  for (int r = 0; r < 4; ++r){
    const int pos = Mg*16 + quad*4 + r;
    float s1t = 0.f, s2t = 0.f, t1t = 0.f;
#pragma unroll
    for (int g = 0; g < 4; ++g){
      s1t += sm.SM1[pos*4 + g];
      s2t += sm.SM2[pos*4 + g];
      t1t += sm.ST [pos*4 + g];
    }
    zacc[r] *= (1.0f / s1t);              // normalize z_q
    if (Ng == 0){
      const float pl = t1t / s2t;
      klsum += pl + LOG_K - m2[r] - __logf(s2t);
      cmsum -= pl;
      if (l15 == 0){
        float bv = -3.0e38f; int bi = 0;
#pragma unroll
        for (int g = 0; g < 4; ++g){
          const float v = sm.AMv[pos*4 + g];
          const int   i = sm.AMi[pos*4 + g];
          if (v > bv || (v == bv && i < bi)){ bv = v; bi = i; }
        }
        out[IDX_OFF + n0 + pos] = (float)bi;
      }
    }
  }
  // KL/commit block reduction (only Ng==0, l15==0 lanes carry data)
  {
    float k = (Ng == 0 && l15 == 0) ? klsum : 0.f;
    float c = (Ng == 0 && l15 == 0) ? cmsum : 0.f;
#pragma unroll
    for (int m = 1; m < 64; m <<= 1){ k += __shfl_xor(k, m, 64); c += __shfl_xor(c, m, 64); }
    if (lane == 0){ sm.RED[wv] = k; sm.RED[wv + 8] = c; }
  }
  // ---- z_q transpose via LDS (C-layout -> [c][w]) then coalesced store
#pragma unroll
  for (int r = 0; r < 4; ++r)
    sm.Z.ZB[(Ng*16 + l15)*33 + Mg*16 + quad*4 + r] = zacc[r];
  __syncthreads();
  if (tid == 0){
    float tk = 0.f, tc = 0.f;
#pragma unroll
    for (int i = 0; i < 8; ++i){ tk += sm.RED[i]; tc += sm.RED[i + 8]; }
    atomicAdd(out + KL_OFF, tk * 0.0625f);
    atomicAdd(out + CM_OFF, tc * 0.0625f);
  }
#pragma unroll
  for (int it = 0; it < 4; ++it){
    const int flat = tid + (it << 9);
    const int c = flat >> 5, w = flat & 31;
    out[((size_t)bb << 18) + (c << 12) + (hh << 6) + w0 + w] = sm.Z.ZB[c*33 + w];
  }
}

extern "C" void kernel_launch(void* const* d_in, const int* in_sizes, int n_in,
                              void* d_out, int out_size, void* d_ws, size_t ws_size,
                              hipStream_t stream){
  const float* ze  = (const float*)d_in[0];
  const float* cbk = (const float*)d_in[1];
  const float* uin = (const float*)d_in[2];
  float* out = (float*)d_out;
  hipMemsetAsync(out + KL_OFF, 0, 2 * sizeof(float), stream);
  vq_mfma<<<dim3(2048), dim3(512), 0, stream>>>(ze, cbk, uin, out);
}

// Round 5
// 294.511 us; speedup vs baseline: 2.1136x; 1.2243x over previous
//
#include <hip/hip_runtime.h>
#include <math.h>
#include <stdint.h>

// N=65536 pos (16x64x64), K=512 slots, D=64.
// out: z_q [16,64,64,64] | idx [16,64,64] | KL | commit   (floats)
#define IDX_OFF 4194304
#define KL_OFF  4259840
#define CM_OFF  4259841
#define LOG_K   6.238324625039508f

typedef _Float16 half8 __attribute__((ext_vector_type(8)));
typedef _Float16 half4 __attribute__((ext_vector_type(4)));
typedef float f32x4 __attribute__((ext_vector_type(4)));

__device__ __forceinline__ float sh16sum(float v){
#pragma unroll
  for (int m = 1; m < 16; m <<= 1) v += __shfl_xor(v, m, 64);
  return v;
}
__device__ __forceinline__ float sh16max(float v){
#pragma unroll
  for (int m = 1; m < 16; m <<= 1) v = fmaxf(v, __shfl_xor(v, m, 64));
  return v;
}

// ws layout: W1H [512][64] half | W1L [512][64] half | W2H [64][512] half | CC[512] float
__global__ __launch_bounds__(64) void vq_pack(const float* __restrict__ cbk, void* __restrict__ ws){
  _Float16* W1H = (_Float16*)ws;
  _Float16* W1L = W1H + 32768;
  _Float16* W2H = W1L + 32768;
  float*    CCw = (float*)(W2H + 32768);
  const int slot = blockIdx.x, c = threadIdx.x;
  const float x = cbk[(slot << 6) + c];
  const _Float16 h = (_Float16)x;
  W1H[(slot << 6) + c] = h;
  W1L[(slot << 6) + c] = (_Float16)(x - (float)h);
  W2H[(c << 9) + slot] = h;
  float s = x * x;
#pragma unroll
  for (int m = 1; m < 64; m <<= 1) s += __shfl_xor(s, m, 64);
  if (c == 0) CCw[slot] = s;
}

struct SMem {
  _Float16 B1H[128*68];   // logits codebook h-plane [slot][c], pitch 68 (8B-al rows, 2-way banks)
  _Float16 B1L[128*68];   // l-plane
  _Float16 B2H[64*132];   // z_q codebook [c][slot], pitch 132
  _Float16 ET[32*144];    // e fp16 [pos][slot], pitch 144 (16B-al rows)
  float ZT[32*66];        // z tile [pos][c] ; reused as ZB [c(64)][33] at the end
  float CC[512];
  float ZZ[32];
  float TM[128];          // per-supertile a-max [pos][Ng]
  float SM1[128], SM2[128], STt[128], AMv[128];
  int   AMi[128];
  float RED[16];
};  // 74688 B -> 2 blocks/CU

__global__ __launch_bounds__(512, 4) void vq_main(
    const float* __restrict__ ze, const float* __restrict__ uin,
    const void* __restrict__ ws, float* __restrict__ out)
{
  __shared__ SMem sm;
  const _Float16* W1H = (const _Float16*)ws;
  const _Float16* W1L = W1H + 32768;
  const _Float16* W2H = W1L + 32768;
  const float*    CCw = (const float*)(W2H + 32768);

  const int tid  = threadIdx.x;
  const int lane = tid & 63, l15 = lane & 15, quad = lane >> 4;
  const int wv   = tid >> 6, Mg = wv >> 2, Ng = wv & 3;
  const int blk  = blockIdx.x;
  const int bb   = blk >> 7, hh = (blk >> 1) & 63, w0 = (blk & 1) << 5;
  const int n0   = blk << 5;

  // ---- stage z tile transposed: ZT[w][c] = ze[bb][c][hh][w0+w]
  {
    const int c = tid >> 3, w4 = (tid & 7) << 2;
    const float4 v = *(const float4*)(ze + ((size_t)bb << 18) + (c << 12) + (hh << 6) + w0 + w4);
    sm.ZT[(w4+0)*66 + c] = v.x;
    sm.ZT[(w4+1)*66 + c] = v.y;
    sm.ZT[(w4+2)*66 + c] = v.z;
    sm.ZT[(w4+3)*66 + c] = v.w;
  }
  sm.CC[tid] = CCw[tid];
  __syncthreads();
  if (tid < 32){
    float s = 0.f;
#pragma unroll 8
    for (int c = 0; c < 64; ++c){ const float v = sm.ZT[tid*66 + c]; s = fmaf(v, v, s); }
    sm.ZZ[tid] = s;
  }
  __syncthreads();

  // ---- hoist z A-frags (fp16 2-term split)
  half8 zh[2], zl[2];
#pragma unroll
  for (int kc = 0; kc < 2; ++kc){
    const float* zp = &sm.ZT[(Mg*16 + l15)*66 + (kc<<5) + (quad<<3)];
#pragma unroll
    for (int j = 0; j < 8; ++j){
      const float x = zp[j];
      const _Float16 h = (_Float16)x;
      zh[kc][j] = h; zl[kc][j] = (_Float16)(x - (float)h);
    }
  }
  const int pos0 = Mg*16 + quad*4;
  float zzv[4];
#pragma unroll
  for (int r = 0; r < 4; ++r) zzv[r] = sm.ZZ[pos0 + r];

  // ---- per-lane online state
  float m1[4], s1[4], s2s[4], t1s[4], am[4]; int ki[4];
#pragma unroll
  for (int r = 0; r < 4; ++r){ m1[r]=-3.0e38f; s1[r]=0.f; s2s[r]=0.f; t1s[r]=0.f; am[r]=-3.0e38f; ki[r]=0; }
  f32x4 zacc = {0.f,0.f,0.f,0.f};

  const float* ub = uin + ((size_t)(n0 + pos0) << 9) + (Ng<<5) + l15;  // +r*512 +nt*16 +st*128
  const int sl_s = tid >> 2, c16 = (tid & 3) << 4;      // B1 staging coords
  const int c_s  = tid >> 3, sg  = (tid & 7) << 4;      // B2 staging coords
  const uint4* s1hp = (const uint4*)(W1H + (sl_s << 6) + c16);
  const uint4* s1lp = (const uint4*)(W1L + (sl_s << 6) + c16);
  const uint4* s2hp = (const uint4*)(W2H + (c_s << 9) + sg);

  // ================= supertile loop (4 x 128 slots) =================
#pragma unroll 1
  for (int st = 0; st < 4; ++st){
    float uval[2][4];
#pragma unroll
    for (int nt = 0; nt < 2; ++nt)
#pragma unroll
      for (int r = 0; r < 4; ++r)
        uval[nt][r] = ub[(st<<7) + (r<<9) + (nt<<4)];   // early issue, consumed late
    __syncthreads();   // protect planes/ET from previous readers
    {  // stage planes (pure copies from pre-packed ws)
      const uint4 a0 = s1hp[(st<<10)+0], a1 = s1hp[(st<<10)+1];
      const uint4 b0 = s1lp[(st<<10)+0], b1 = s1lp[(st<<10)+1];
      const uint4 c0 = s2hp[(st<<4)+0],  c1 = s2hp[(st<<4)+1];
      uint2* d1h = (uint2*)&sm.B1H[sl_s*68 + c16];
      uint2* d1l = (uint2*)&sm.B1L[sl_s*68 + c16];
      uint2* d2h = (uint2*)&sm.B2H[c_s*132 + sg];
      d1h[0] = make_uint2(a0.x,a0.y); d1h[1] = make_uint2(a0.z,a0.w);
      d1h[2] = make_uint2(a1.x,a1.y); d1h[3] = make_uint2(a1.z,a1.w);
      d1l[0] = make_uint2(b0.x,b0.y); d1l[1] = make_uint2(b0.z,b0.w);
      d1l[2] = make_uint2(b1.x,b1.y); d1l[3] = make_uint2(b1.z,b1.w);
      d2h[0] = make_uint2(c0.x,c0.y); d2h[1] = make_uint2(c0.z,c0.w);
      d2h[2] = make_uint2(c1.x,c1.y); d2h[3] = make_uint2(c1.z,c1.w);
    }
    __syncthreads();

    // ---- logits MFMA (3-term split) + gumbel
    float lv[2][4], av[2][4], llv[2][4];
#pragma unroll
    for (int nt = 0; nt < 2; ++nt){
      f32x4 acc = {0.f,0.f,0.f,0.f};
      const int slotl = (Ng<<5) + (nt<<4) + l15;
#pragma unroll
      for (int kc = 0; kc < 2; ++kc){
        const _Float16* bp = &sm.B1H[slotl*68 + (kc<<5) + (quad<<3)];
        const _Float16* lp = &sm.B1L[slotl*68 + (kc<<5) + (quad<<3)];
        const half4 h0 = *(const half4*)bp, h1 = *(const half4*)(bp+4);
        const half4 g0 = *(const half4*)lp, g1 = *(const half4*)(lp+4);
        const half8 bh = __builtin_shufflevector(h0, h1, 0,1,2,3,4,5,6,7);
        const half8 bl = __builtin_shufflevector(g0, g1, 0,1,2,3,4,5,6,7);
        acc = __builtin_amdgcn_mfma_f32_16x16x32_f16(zh[kc], bh, acc, 0,0,0);
        acc = __builtin_amdgcn_mfma_f32_16x16x32_f16(zl[kc], bh, acc, 0,0,0);
        acc = __builtin_amdgcn_mfma_f32_16x16x32_f16(zh[kc], bl, acc, 0,0,0);
      }
      const float ccv = sm.CC[(st<<7) + slotl];
#pragma unroll
      for (int r = 0; r < 4; ++r){
        const float l = fmaf(2.f, acc[r], -ccv - zzv[r]);
        const float llu = -__logf(uval[nt][r] + 1e-10f) + 1e-10f;
        lv[nt][r] = l; llv[nt][r] = llu;
        av[nt][r] = l - __logf(llu);          // a = logit + gumbel
      }
    }
    // ---- cross-wave running max of a (needed: shared e-scale for z_q MFMA)
#pragma unroll
    for (int r = 0; r < 4; ++r){
      const float ta = sh16max(fmaxf(av[0][r], av[1][r]));
      if (l15 == 0) sm.TM[(pos0 + r)*4 + Ng] = ta;
    }
    __syncthreads();
#pragma unroll
    for (int r = 0; r < 4; ++r){
      const int pos = pos0 + r;
      float M = m1[r];
#pragma unroll
      for (int g = 0; g < 4; ++g) M = fmaxf(M, sm.TM[pos*4 + g]);
      const float sc1h = __expf(m1[r] - M);   // half-scale: probs ref
      const float sc1  = sc1h * sc1h;         // full-scale: gumbel ref (T=0.5 -> x2)
      m1[r] = M;
      s1[r] *= sc1; zacc[r] *= sc1; s2s[r] *= sc1h; t1s[r] *= sc1h;
      const float t0  = __expf(av[0][r] - M);
      const float t1e = __expf(av[1][r] - M);
      const float e0 = t0*t0, e1 = t1e*t1e;   // e = exp(2(a-M))
      s1[r] += e0 + e1;
      sm.ET[pos*144 + (Ng<<5) + l15]      = (_Float16)e0;
      sm.ET[pos*144 + (Ng<<5) + 16 + l15] = (_Float16)e1;
      const float p0 = t0*llv[0][r], p1 = t1e*llv[1][r];   // p = exp(l - M), exact
      s2s[r] += p0 + p1;
      t1s[r] = fmaf(p0, lv[0][r], fmaf(p1, lv[1][r], t1s[r]));
      float bv; int bi;
      const int sbase = (st<<7) + (Ng<<5) + l15;
      if (av[0][r] >= av[1][r]) { bv = av[0][r]; bi = sbase; }
      else                      { bv = av[1][r]; bi = sbase + 16; }
      if (bv > am[r]){ am[r] = bv; ki[r] = bi; }   // strict: earlier (smaller k) wins ties
    }
    __syncthreads();   // e-tile complete
    // ---- z_q MFMA (h-only codebook), K=128 this supertile
#pragma unroll
    for (int kc3 = 0; kc3 < 4; ++kc3){
      const half8 af = *(const half8*)&sm.ET[(Mg*16 + l15)*144 + (kc3<<5) + (quad<<3)];
      const _Float16* bp = &sm.B2H[(Ng*16 + l15)*132 + (kc3<<5) + (quad<<3)];
      const half4 h0 = *(const half4*)bp, h1 = *(const half4*)(bp + 4);
      const half8 bh = __builtin_shufflevector(h0, h1, 0,1,2,3,4,5,6,7);
      zacc = __builtin_amdgcn_mfma_f32_16x16x32_f16(af, bh, zacc, 0,0,0);
    }
  }
  // ================= end supertile loop =================

  // ---- one-time reductions
#pragma unroll
  for (int r = 0; r < 4; ++r){
    s1[r]  = sh16sum(s1[r]);
    s2s[r] = sh16sum(s2s[r]);
    t1s[r] = sh16sum(t1s[r]);
#pragma unroll
    for (int m = 1; m < 16; m <<= 1){
      const float vo = __shfl_xor(am[r], m, 64);
      const int   io = __shfl_xor(ki[r], m, 64);
      if (vo > am[r] || (vo == am[r] && io < ki[r])){ am[r] = vo; ki[r] = io; }
    }
    if (l15 == 0){
      const int pos = pos0 + r;
      sm.SM1[pos*4+Ng] = s1[r];
      sm.SM2[pos*4+Ng] = s2s[r];
      sm.STt[pos*4+Ng] = t1s[r];
      sm.AMv[pos*4+Ng] = am[r];
      sm.AMi[pos*4+Ng] = ki[r];
    }
  }
  __syncthreads();

  float kl = 0.f, cm = 0.f;
#pragma unroll
  for (int r = 0; r < 4; ++r){
    const int pos = pos0 + r;
    float s1t = 0.f, s2t = 0.f, t1t = 0.f;
#pragma unroll
    for (int g = 0; g < 4; ++g){ s1t += sm.SM1[pos*4+g]; s2t += sm.SM2[pos*4+g]; t1t += sm.STt[pos*4+g]; }
    zacc[r] *= (1.0f / s1t);
    if (Ng == 0){
      const float pl = t1t / s2t;                       // sum p*logit (normalized)
      kl += pl + LOG_K - m1[r] - __logf(s2t);           // sum p*(log p + logK)
      cm -= pl;                                         // sum p*dist = -sum p*logit
      if (l15 == 0){
        float bv = -3.0e38f; int bi = 0;
#pragma unroll
        for (int g = 0; g < 4; ++g){
          const float v = sm.AMv[pos*4+g]; const int i = sm.AMi[pos*4+g];
          if (v > bv || (v == bv && i < bi)){ bv = v; bi = i; }
        }
        out[IDX_OFF + n0 + pos] = (float)bi;
      }
    }
  }
  {
    float k = (Ng==0 && l15==0) ? kl : 0.f;
    float c = (Ng==0 && l15==0) ? cm : 0.f;
#pragma unroll
    for (int m = 1; m < 64; m <<= 1){ k += __shfl_xor(k,m,64); c += __shfl_xor(c,m,64); }
    if (lane == 0){ sm.RED[wv] = k; sm.RED[wv+8] = c; }
  }
  // ---- z_q transpose via reused ZT region: ZB[c(64)][33]
  float* ZB = sm.ZT;
#pragma unroll
  for (int r = 0; r < 4; ++r)
    ZB[(Ng*16 + l15)*33 + pos0 + r] = zacc[r];
  __syncthreads();
  if (tid == 0){
    float tk = 0.f, tc = 0.f;
#pragma unroll
    for (int i = 0; i < 8; ++i){ tk += sm.RED[i]; tc += sm.RED[i+8]; }
    atomicAdd(out + KL_OFF, tk * 0.0625f);
    atomicAdd(out + CM_OFF, tc * 0.0625f);
  }
#pragma unroll
  for (int it = 0; it < 4; ++it){
    const int flat = tid + (it << 9);
    const int c = flat >> 5, w = flat & 31;
    out[((size_t)bb << 18) + (c << 12) + (hh << 6) + w0 + w] = ZB[c*33 + w];
  }
}

extern "C" void kernel_launch(void* const* d_in, const int* in_sizes, int n_in,
                              void* d_out, int out_size, void* d_ws, size_t ws_size,
                              hipStream_t stream){
  const float* ze  = (const float*)d_in[0];
  const float* cbk = (const float*)d_in[1];
  const float* uin = (const float*)d_in[2];
  float* out = (float*)d_out;
  hipMemsetAsync(out + KL_OFF, 0, 2 * sizeof(float), stream);
  vq_pack<<<dim3(512), dim3(64), 0, stream>>>(cbk, d_ws);
  vq_main<<<dim3(2048), dim3(512), 0, stream>>>(ze, uin, d_ws, out);
}